// Round 8
// baseline (360.314 us; speedup 1.0000x reference)
//
#include <hip/hip_runtime.h>

// ROUND 8 = DIAGNOSTIC ABLATION ROUND.
// conv_ablate<V> variants (write garbage to d_out, later overwritten):
//   V1: STAGE+vmcnt+barrier only       (global->LDS path cost)
//   V2: ds_read+MFMA+barrier only      (LDS->MFMA path cost)
//   V3: STAGE+vmcnt+barrier+MFMA       (no per-iter ds_read)
//   V4: MFMA+barrier only              (pipe + lockstep floor)
// conv_main (unmodified round-6 kernel, best so far: 99us) runs LAST and
// rewrites every output element -> final output correct.

using bf16x8 = __attribute__((ext_vector_type(8))) __bf16;
using f32x4  = __attribute__((ext_vector_type(4))) float;
using f32x16 = __attribute__((ext_vector_type(16))) float;

constexpr int CIN  = 128;
constexpr int HW   = 64;
constexpr int COUT = 256;
constexpr int OW   = 62;
constexpr int NS   = 62 * 62;          // 3844
constexpr int NTOT = 32 * NS;          // 123008
constexpr int KTOT = 9 * CIN;          // 1152
constexpr int BM = 128, BN = 128, BK = 64;
constexpr int NT = KTOT / BK;          // 18 K-tiles
constexpr int NWG = 2 * (NTOT / BN);   // 1922

constexpr size_t AP_BYTES = (size_t)COUT * KTOT * 2;            // 589824
constexpr size_t XP_BYTES = (size_t)32 * HW * HW * CIN * 2;     // 33554432
constexpr size_t WS_NEEDED = AP_BYTES + XP_BYTES;

constexpr int BUF  = 32768;            // per K-tile buffer: A 16KB + B 16KB
constexpr int BOFF = 16384;            // B offset inside buffer

__device__ __forceinline__ unsigned short f2bf(float f) {
  unsigned u = __float_as_uint(f);
  u += 0x7fffu + ((u >> 16) & 1u);     // RNE
  return (unsigned short)(u >> 16);
}
__device__ __forceinline__ unsigned pack2(float a, float b) {
  return (unsigned)f2bf(a) | ((unsigned)f2bf(b) << 16);
}

__device__ __forceinline__ void gld16(const void* g, void* l) {
  __builtin_amdgcn_global_load_lds(
      (const __attribute__((address_space(1))) unsigned int*)g,
      (__attribute__((address_space(3))) unsigned int*)l, 16, 0, 0);
}

// ---------------- prepack kernels ----------------

__global__ __launch_bounds__(256)
void prepack_w(const float* __restrict__ w, unsigned* __restrict__ ap32) {
  const int idx = blockIdx.x * 256 + threadIdx.x;     // 0..147455
  const int co  = idx / 576;
  const int k2  = idx - co * 576;
  const int k   = k2 * 2;
  const int tap = k >> 7;
  const int ci  = k & 127;
  const float v0 = w[(co * 128 + ci) * 9 + tap];
  const float v1 = w[(co * 128 + ci + 1) * 9 + tap];
  ap32[idx] = pack2(v0, v1);
}

__global__ __launch_bounds__(256)
void prepack_x(const float* __restrict__ x, unsigned* __restrict__ xp32) {
  const int bh = blockIdx.x;           // b*64 + h
  const int b  = bh >> 6, h = bh & 63;
  const int t  = threadIdx.x;
  const int c  = t & 63;               // ci-pair index (ci = 2c, 2c+1)
  const int w0 = (t >> 6) * 16;

  const float* p0 = x + (((size_t)(b * 128 + 2 * c) * HW) + h) * HW + w0;
  const float* p1 = p0 + (size_t)HW * HW;
  float r0[16], r1[16];
#pragma unroll
  for (int j = 0; j < 4; ++j) {
    *reinterpret_cast<float4*>(&r0[j * 4]) = reinterpret_cast<const float4*>(p0)[j];
    *reinterpret_cast<float4*>(&r1[j * 4]) = reinterpret_cast<const float4*>(p1)[j];
  }
  unsigned* o = xp32 + ((size_t)bh * HW + w0) * 64 + c;
#pragma unroll
  for (int j = 0; j < 16; ++j)
    o[j * 64] = pack2(r0[j], r1[j]);
}

// ---------------- main kernel (round-6, unmodified, proven 99us) ----------------

__global__ __launch_bounds__(256, 2)
void conv_main(const unsigned short* __restrict__ Ap,
               const unsigned short* __restrict__ Xp,
               float* __restrict__ out) {
  __shared__ __align__(16) char lds[2 * BUF];   // 64 KiB -> 2 blocks/CU

  const int tid  = threadIdx.x;
  const int lane = tid & 63;
  const int wid  = tid >> 6;       // 0..3
  const int wm   = wid >> 1;
  const int wn   = wid & 1;

  int wg;
  {
    const int f = blockIdx.x;
    constexpr int q = NWG / 8, r = NWG % 8;
    const int xc = f % 8, p = f / 8;
    wg = (xc < r ? xc * (q + 1) : r * (q + 1) + (xc - r) * q) + p;
  }
  const int co_base = (wg & 1) * BM;
  const int n_base  = (wg >> 1) * BN;

  const int l3  = lane >> 3;
  const int sw8 = ((lane & 7) ^ l3) * 8;
  int aoff[4];
  unsigned xoff[4];
#pragma unroll
  for (int q = 0; q < 4; ++q) {
    const int rr = wid * 32 + q * 8 + l3;
    aoff[q] = (co_base + rr) * KTOT + sw8;
    const unsigned n  = n_base + rr;
    const unsigned bi = n / NS;
    const unsigned s0 = n - bi * NS;
    const unsigned oh = s0 / OW;
    const unsigned ww = s0 - oh * OW;
    xoff[q] = ((bi * HW + oh) * HW + ww) * CIN + sw8;
  }

  const int cl = lane & 31;
  const int gl = lane >> 5;
  int sA[4];
#pragma unroll
  for (int kf = 0; kf < 4; ++kf)
    sA[kf] = ((kf * 2 + gl) ^ (lane & 7)) * 16;
  const int abase = (wm * 64 + cl) * 128;
  const int bbase = BOFF + (wn * 64 + cl) * 128;

  f32x16 acc[2][2] = {};

  auto STAGE = [&](int t, char* dst) {
    const int tap = t >> 1;
    const int kh  = tap / 3;
    const int kw  = tap - kh * 3;
    const int ak  = tap * CIN + (t & 1) * 64;
    const int xk  = (kh * HW + kw) * CIN + (t & 1) * 64;
#pragma unroll
    for (int q = 0; q < 4; ++q)
      gld16(Ap + aoff[q] + ak, dst + (wid * 32 + q * 8) * 128);
#pragma unroll
    for (int q = 0; q < 4; ++q)
      gld16(Xp + xoff[q] + xk, dst + BOFF + (wid * 32 + q * 8) * 128);
  };

  STAGE(0, lds);

#pragma unroll
  for (int t = 0; t < NT; ++t) {
    const char* cur = lds + (t & 1) * BUF;
    asm volatile("s_waitcnt vmcnt(0)" ::: "memory");
    __builtin_amdgcn_s_barrier();
    if (t + 1 < NT) STAGE(t + 1, lds + ((t + 1) & 1) * BUF);

    bf16x8 a[2][4], b[2][4];
#pragma unroll
    for (int mt = 0; mt < 2; ++mt)
#pragma unroll
      for (int kf = 0; kf < 4; ++kf)
        a[mt][kf] = *reinterpret_cast<const bf16x8*>(cur + abase + mt * 4096 + sA[kf]);
#pragma unroll
    for (int nt = 0; nt < 2; ++nt)
#pragma unroll
      for (int kf = 0; kf < 4; ++kf)
        b[nt][kf] = *reinterpret_cast<const bf16x8*>(cur + bbase + nt * 4096 + sA[kf]);

#pragma unroll
    for (int kf = 0; kf < 4; ++kf)
#pragma unroll
      for (int mt = 0; mt < 2; ++mt)
#pragma unroll
        for (int nt = 0; nt < 2; ++nt)
          acc[mt][nt] = __builtin_amdgcn_mfma_f32_32x32x16_bf16(
              a[mt][kf], b[nt][kf], acc[mt][nt], 0, 0, 0);
  }

#pragma unroll
  for (int mt = 0; mt < 2; ++mt)
#pragma unroll
    for (int nt = 0; nt < 2; ++nt) {
      const unsigned n  = n_base + wn * 64 + nt * 32 + cl;
      const unsigned b2 = n / NS;
      const unsigned s2 = n - b2 * NS;
      float* op = out + (size_t)b2 * (COUT * NS) + s2
                      + (size_t)(co_base + wm * 64 + mt * 32 + gl * 4) * NS;
#pragma unroll
      for (int r = 0; r < 16; ++r)
        op[((r & 3) + 8 * (r >> 2)) * NS] = acc[mt][nt][r];
    }
}

// ---------------- ablation variants ----------------
// V1: stage only | V2: ds+mfma only | V3: stage+mfma (preloaded frags) |
// V4: mfma only (preloaded frags). Same grid/geometry/swizzle as conv_main.

template <int V>
__global__ __launch_bounds__(256, 2)
void conv_ablate(const unsigned short* __restrict__ Ap,
                 const unsigned short* __restrict__ Xp,
                 float* __restrict__ out) {
  constexpr bool DO_STAGE = (V == 1 || V == 3);
  constexpr bool DO_DS    = (V == 2);
  constexpr bool DO_MFMA  = (V != 1);

  __shared__ __align__(16) char lds[2 * BUF];

  const int tid  = threadIdx.x;
  const int lane = tid & 63;
  const int wid  = tid >> 6;
  const int wm   = wid >> 1;
  const int wn   = wid & 1;

  int wg;
  {
    const int f = blockIdx.x;
    constexpr int q = NWG / 8, r = NWG % 8;
    const int xc = f % 8, p = f / 8;
    wg = (xc < r ? xc * (q + 1) : r * (q + 1) + (xc - r) * q) + p;
  }
  const int co_base = (wg & 1) * BM;
  const int n_base  = (wg >> 1) * BN;

  const int l3  = lane >> 3;
  const int sw8 = ((lane & 7) ^ l3) * 8;
  int aoff[4];
  unsigned xoff[4];
#pragma unroll
  for (int q = 0; q < 4; ++q) {
    const int rr = wid * 32 + q * 8 + l3;
    aoff[q] = (co_base + rr) * KTOT + sw8;
    const unsigned n  = n_base + rr;
    const unsigned bi = n / NS;
    const unsigned s0 = n - bi * NS;
    const unsigned oh = s0 / OW;
    const unsigned ww = s0 - oh * OW;
    xoff[q] = ((bi * HW + oh) * HW + ww) * CIN + sw8;
  }

  const int cl = lane & 31;
  const int gl = lane >> 5;
  int sA[4];
#pragma unroll
  for (int kf = 0; kf < 4; ++kf)
    sA[kf] = ((kf * 2 + gl) ^ (lane & 7)) * 16;
  const int abase = (wm * 64 + cl) * 128;
  const int bbase = BOFF + (wn * 64 + cl) * 128;

  f32x16 acc[2][2] = {};

  auto STAGE = [&](int t, char* dst) {
    const int tap = t >> 1;
    const int kh  = tap / 3;
    const int kw  = tap - kh * 3;
    const int ak  = tap * CIN + (t & 1) * 64;
    const int xk  = (kh * HW + kw) * CIN + (t & 1) * 64;
#pragma unroll
    for (int q = 0; q < 4; ++q)
      gld16(Ap + aoff[q] + ak, dst + (wid * 32 + q * 8) * 128);
#pragma unroll
    for (int q = 0; q < 4; ++q)
      gld16(Xp + xoff[q] + xk, dst + BOFF + (wid * 32 + q * 8) * 128);
  };

  if (DO_STAGE) {
    STAGE(0, lds);
    asm volatile("s_waitcnt vmcnt(0)" ::: "memory");
  }
  __builtin_amdgcn_s_barrier();

  // preloaded fragments for V3/V4 (read once; garbage OK for V4)
  bf16x8 pa[2][4], pb[2][4];
  if (DO_MFMA && !DO_DS) {
#pragma unroll
    for (int mt = 0; mt < 2; ++mt)
#pragma unroll
      for (int kf = 0; kf < 4; ++kf)
        pa[mt][kf] = *reinterpret_cast<const bf16x8*>(lds + abase + mt * 4096 + sA[kf]);
#pragma unroll
    for (int nt = 0; nt < 2; ++nt)
#pragma unroll
      for (int kf = 0; kf < 4; ++kf)
        pb[nt][kf] = *reinterpret_cast<const bf16x8*>(lds + bbase + nt * 4096 + sA[kf]);
  }

#pragma unroll
  for (int t = 0; t < NT; ++t) {
    const char* cur = lds + (t & 1) * BUF;
    if (DO_STAGE) asm volatile("s_waitcnt vmcnt(0)" ::: "memory");
    __builtin_amdgcn_s_barrier();
    if (DO_STAGE && t + 1 < NT) STAGE(t + 1, lds + ((t + 1) & 1) * BUF);

    bf16x8 a[2][4], b[2][4];
    if (DO_DS) {
#pragma unroll
      for (int mt = 0; mt < 2; ++mt)
#pragma unroll
        for (int kf = 0; kf < 4; ++kf)
          a[mt][kf] = *reinterpret_cast<const bf16x8*>(cur + abase + mt * 4096 + sA[kf]);
#pragma unroll
      for (int nt = 0; nt < 2; ++nt)
#pragma unroll
        for (int kf = 0; kf < 4; ++kf)
          b[nt][kf] = *reinterpret_cast<const bf16x8*>(cur + bbase + nt * 4096 + sA[kf]);
    }

    if (DO_MFMA) {
#pragma unroll
      for (int kf = 0; kf < 4; ++kf)
#pragma unroll
        for (int mt = 0; mt < 2; ++mt)
#pragma unroll
          for (int nt = 0; nt < 2; ++nt)
            acc[mt][nt] = __builtin_amdgcn_mfma_f32_32x32x16_bf16(
                DO_DS ? a[mt][kf] : pa[mt][kf],
                DO_DS ? b[nt][kf] : pb[nt][kf],
                acc[mt][nt], 0, 0, 0);
    }
  }

  // epilogue identical to conv_main (writes garbage/zeros; conv_main rewrites)
#pragma unroll
  for (int mt = 0; mt < 2; ++mt)
#pragma unroll
    for (int nt = 0; nt < 2; ++nt) {
      const unsigned n  = n_base + wn * 64 + nt * 32 + cl;
      const unsigned b2 = n / NS;
      const unsigned s2 = n - b2 * NS;
      float* op = out + (size_t)b2 * (COUT * NS) + s2
                      + (size_t)(co_base + wm * 64 + mt * 32 + gl * 4) * NS;
#pragma unroll
      for (int r = 0; r < 16; ++r)
        op[((r & 3) + 8 * (r >> 2)) * NS] = acc[mt][nt][r];
    }
}

// ---------------- fallback (no-ws path, round-1 proven) ----------------

__global__ __launch_bounds__(256)
void conv_fallback(const float* __restrict__ x, const float* __restrict__ w,
                   float* __restrict__ out) {
  __shared__ __align__(16) unsigned short As[128 * 32];
  __shared__ __align__(16) unsigned short Bs[128 * 32];

  const int t    = threadIdx.x;
  const int lane = t & 63;
  const int wid  = t >> 6;
  const int wm   = wid >> 1;
  const int wn   = wid & 1;
  const int co_base = blockIdx.x * 128;
  const int n_base  = blockIdx.y * 128;

  const int bn  = t & 127;
  const int bg0 = t >> 7;
  const unsigned n0   = n_base + bn;
  const unsigned bidx = n0 / NS;
  const unsigned s0   = n0 - bidx * NS;
  const unsigned oh   = s0 / OW;
  const unsigned ow   = s0 - oh * OW;
  const float* xb = x + (bidx * (CIN * HW * HW) + oh * HW + ow);

  const int am  = t & 127;
  const int ag0 = (t >> 7) * 2;
  const float* wb = w + (co_base + am) * KTOT;

  f32x4 acc[4][4] = {};

  for (int ks = 0; ks < 36; ++ks) {
    const int tap = ks >> 2;
    const int ci0 = (ks & 3) * 32;
    const int kh  = tap / 3;
    const int kw  = tap - kh * 3;
    const int xo  = kh * HW + kw;

    float av[2][8], bv[2][8];
#pragma unroll
    for (int gi = 0; gi < 2; ++gi) {
      const int g = ag0 + gi;
#pragma unroll
      for (int j = 0; j < 8; ++j)
        av[gi][j] = wb[(ci0 + g * 8 + j) * 9 + tap];
    }
#pragma unroll
    for (int gi = 0; gi < 2; ++gi) {
      const int g = bg0 + gi * 2;
#pragma unroll
      for (int j = 0; j < 8; ++j)
        bv[gi][j] = xb[xo + (ci0 + g * 8 + j) * (HW * HW)];
    }

    __syncthreads();

#pragma unroll
    for (int gi = 0; gi < 2; ++gi) {
      const int g = ag0 + gi;
      uint4 pv;
      pv.x = pack2(av[gi][0], av[gi][1]);
      pv.y = pack2(av[gi][2], av[gi][3]);
      pv.z = pack2(av[gi][4], av[gi][5]);
      pv.w = pack2(av[gi][6], av[gi][7]);
      *reinterpret_cast<uint4*>(&As[am * 32 + ((g ^ ((am >> 1) & 3)) << 3)]) = pv;
    }
#pragma unroll
    for (int gi = 0; gi < 2; ++gi) {
      const int g = bg0 + gi * 2;
      uint4 pv;
      pv.x = pack2(bv[gi][0], bv[gi][1]);
      pv.y = pack2(bv[gi][2], bv[gi][3]);
      pv.z = pack2(bv[gi][4], bv[gi][5]);
      pv.w = pack2(bv[gi][6], bv[gi][7]);
      *reinterpret_cast<uint4*>(&Bs[bn * 32 + ((g ^ ((bn >> 1) & 3)) << 3)]) = pv;
    }

    __syncthreads();

    bf16x8 af[4], bfr[4];
    const int g = lane >> 4;
#pragma unroll
    for (int mi = 0; mi < 4; ++mi) {
      const int m = wm * 64 + mi * 16 + (lane & 15);
      af[mi] = *reinterpret_cast<const bf16x8*>(&As[m * 32 + ((g ^ ((m >> 1) & 3)) << 3)]);
    }
#pragma unroll
    for (int ni = 0; ni < 4; ++ni) {
      const int nn = wn * 64 + ni * 16 + (lane & 15);
      bfr[ni] = *reinterpret_cast<const bf16x8*>(&Bs[nn * 32 + ((g ^ ((nn >> 1) & 3)) << 3)]);
    }
#pragma unroll
    for (int mi = 0; mi < 4; ++mi)
#pragma unroll
      for (int ni = 0; ni < 4; ++ni)
        acc[mi][ni] = __builtin_amdgcn_mfma_f32_16x16x32_bf16(af[mi], bfr[ni],
                                                              acc[mi][ni], 0, 0, 0);
  }

#pragma unroll
  for (int ni = 0; ni < 4; ++ni) {
    const unsigned n  = n_base + wn * 64 + ni * 16 + (lane & 15);
    const unsigned b2 = n / NS;
    const unsigned s2 = n - b2 * NS;
    float* op = out + (size_t)b2 * (COUT * NS) + s2
                    + (size_t)(co_base + wm * 64 + (lane >> 4) * 4) * NS;
#pragma unroll
    for (int mi = 0; mi < 4; ++mi)
#pragma unroll
      for (int r = 0; r < 4; ++r)
        op[(mi * 16 + r) * NS] = acc[mi][ni][r];
  }
}

extern "C" void kernel_launch(void* const* d_in, const int* in_sizes, int n_in,
                              void* d_out, int out_size, void* d_ws, size_t ws_size,
                              hipStream_t stream) {
  const float* x = (const float*)d_in[0];   // [32,128,64,64]
  const float* w = (const float*)d_in[1];   // [256,128,3,3]
  float* out = (float*)d_out;               // [32,256,62,62]

  if (ws_size >= WS_NEEDED) {
    unsigned* ap32 = (unsigned*)d_ws;
    unsigned short* Ap = (unsigned short*)d_ws;
    unsigned short* Xp = (unsigned short*)((char*)d_ws + AP_BYTES);
    unsigned* xp32 = (unsigned*)Xp;
    prepack_w<<<576, 256, 0, stream>>>(w, ap32);
    prepack_x<<<32 * HW, 256, 0, stream>>>(x, xp32);
    // ---- ablation dispatches (outputs overwritten by conv_main below) ----
    conv_ablate<1><<<dim3(NWG), 256, 0, stream>>>(Ap, Xp, out);
    conv_ablate<2><<<dim3(NWG), 256, 0, stream>>>(Ap, Xp, out);
    conv_ablate<3><<<dim3(NWG), 256, 0, stream>>>(Ap, Xp, out);
    conv_ablate<4><<<dim3(NWG), 256, 0, stream>>>(Ap, Xp, out);
    // ---- real kernel (round-6 proven), rewrites all outputs ----
    conv_main<<<dim3(NWG), 256, 0, stream>>>(Ap, Xp, out);
  } else {
    conv_fallback<<<dim3(2, NTOT / 128), 256, 0, stream>>>(x, w, out);
  }
}

// Round 9
// 114.740 us; speedup vs baseline: 3.1403x; 3.1403x over previous
//
#include <hip/hip_runtime.h>

// Implicit-GEMM conv2d via bf16 MFMA (32x32x16) with HALO-LDS B-path.
// Panel = 124 n-values (2 output rows, 992 panels exact, never cross batch).
// Per ci-chunk (32 ci): stage halo x-tile [4 rows][64 ow][32 ci] = 16KB ONCE,
// 9 taps read it from LDS -> B staging bytes cut 4.5x vs per-tap staging.
// A-path: R7-proven paired-row LDS layout, staged per (chunk,tap) step.
// Block: 256(co) x 124(n,pad 128), 256 thr / 4 waves (2M x 2N),
// wave tile 128x64, acc 4x2 f32x16. LDS: A dbuf 2x16KB + halo dbuf 2x16KB
// = 64KB -> 2 blocks/CU. One raw s_barrier per step, stage-after-barrier,
// counted vmcnt(4) on the step after a halo prefetch.
//   A' [256][1152] bf16 (k = tap*128+ci)   xp [32][64][64][128] bf16 NHWC

using bf16x8 = __attribute__((ext_vector_type(8))) __bf16;
using f32x4  = __attribute__((ext_vector_type(4))) float;
using f32x16 = __attribute__((ext_vector_type(16))) float;

constexpr int CIN  = 128;
constexpr int HW   = 64;
constexpr int COUT = 256;
constexpr int OW   = 62;
constexpr int NS   = 62 * 62;          // 3844
constexpr int NTOT = 32 * NS;          // 123008
constexpr int KTOT = 9 * CIN;          // 1152
constexpr int BNR  = 124;              // real n per panel (2 output rows)
constexpr int NPAN = NTOT / BNR;       // 992 (exact; 31 panels/batch)

constexpr size_t AP_BYTES = (size_t)COUT * KTOT * 2;            // 589824
constexpr size_t XP_BYTES = (size_t)32 * HW * HW * CIN * 2;     // 33554432
constexpr size_t WS_NEEDED = AP_BYTES + XP_BYTES;

__device__ __forceinline__ unsigned short f2bf(float f) {
  unsigned u = __float_as_uint(f);
  u += 0x7fffu + ((u >> 16) & 1u);     // RNE
  return (unsigned short)(u >> 16);
}
__device__ __forceinline__ unsigned pack2(float a, float b) {
  return (unsigned)f2bf(a) | ((unsigned)f2bf(b) << 16);
}

__device__ __forceinline__ void gld16(const void* g, void* l) {
  __builtin_amdgcn_global_load_lds(
      (const __attribute__((address_space(1))) unsigned int*)g,
      (__attribute__((address_space(3))) unsigned int*)l, 16, 0, 0);
}

// ---------------- prepack kernels ----------------

__global__ __launch_bounds__(256)
void prepack_w(const float* __restrict__ w, unsigned* __restrict__ ap32) {
  const int idx = blockIdx.x * 256 + threadIdx.x;     // 0..147455
  const int co  = idx / 576;
  const int k2  = idx - co * 576;
  const int k   = k2 * 2;
  const int tap = k >> 7;
  const int ci  = k & 127;
  const float v0 = w[(co * 128 + ci) * 9 + tap];
  const float v1 = w[(co * 128 + ci + 1) * 9 + tap];
  ap32[idx] = pack2(v0, v1);
}

__global__ __launch_bounds__(256)
void prepack_x(const float* __restrict__ x, unsigned* __restrict__ xp32) {
  const int bh = blockIdx.x;           // b*64 + h
  const int b  = bh >> 6, h = bh & 63;
  const int t  = threadIdx.x;
  const int c  = t & 63;               // ci-pair index
  const int w0 = (t >> 6) * 16;

  const float* p0 = x + (((size_t)(b * 128 + 2 * c) * HW) + h) * HW + w0;
  const float* p1 = p0 + (size_t)HW * HW;
  float r0[16], r1[16];
#pragma unroll
  for (int j = 0; j < 4; ++j) {
    *reinterpret_cast<float4*>(&r0[j * 4]) = reinterpret_cast<const float4*>(p0)[j];
    *reinterpret_cast<float4*>(&r1[j * 4]) = reinterpret_cast<const float4*>(p1)[j];
  }
  unsigned* o = xp32 + ((size_t)bh * HW + w0) * 64 + c;
#pragma unroll
  for (int j = 0; j < 16; ++j)
    o[j * 64] = pack2(r0[j], r1[j]);
}

// ---------------- main kernel ----------------

__global__ __launch_bounds__(256, 2)
void conv_main(const unsigned short* __restrict__ Ap,
               const unsigned short* __restrict__ Xp,
               float* __restrict__ out) {
  // LDS: abuf0 | abuf1 | hbuf0 | hbuf1, 16KB each.
  // A layout: 128B line = 2 co-rows; slotpos = (row&1)*4 + (g ^ (line&3)).
  // Halo layout: 128B line = 2 ow; line = r*32 + (ow>>1);
  //              slotpos = (ow&1)*4 + (g ^ (line&3)); g = ci-slot (8 elems).
  __shared__ __align__(16) char lds[65536];

  const int tid  = threadIdx.x;
  const int lane = tid & 63;
  const int wid  = tid >> 6;       // 0..3
  const int wm   = wid >> 1;       // co half (128 rows)
  const int wn   = wid & 1;        // n half (64 cols)

  // bijective XCD swizzle (992 = 8*124)
  int wg; { const int f = blockIdx.x; wg = (f & 7) * 124 + (f >> 3); }
  const int bi  = wg / 31;               // batch
  const int oh0 = (wg - bi * 31) * 2;    // first output row of panel
  const int n_base = wg * BNR;
  (void)n_base;

  // ---- A staging decode (R7-proven) ----
  const int lrow2 = ((lane >> 3) << 1) + ((lane >> 2) & 1);
  const int g8a   = ((lane & 3) ^ ((lane >> 3) & 3)) * 8;
  int aoff[4];
#pragma unroll
  for (int q = 0; q < 4; ++q) {
    const int row = (wid * 4 + q) * 16 + lrow2;          // co 0..255
    aoff[q] = row * KTOT + g8a;
  }

  // ---- halo staging decode ----
  int hsrc[4];
#pragma unroll
  for (int q = 0; q < 4; ++q) {
    const int line = (wid * 4 + q) * 8 + (lane >> 3);    // 0..127
    const int r    = line >> 5;                          // 0..3
    const int owp  = line & 31;
    const int ow   = owp * 2 + ((lane >> 2) & 1);        // 0..63
    hsrc[q] = ((bi * 64 + oh0 + r) * HW + ow) * CIN
            + (((lane & 3) ^ (line & 3)) << 3);
  }

  // ---- A fragment addressing (R7-proven) ----
  const int cl = lane & 31;
  const int gl = lane >> 5;
  const int q4 = (cl >> 1) & 3;
  const int sw0 = ((gl)     ^ q4) * 16;
  const int sw1 = ((2 + gl) ^ q4) * 16;
  const int ABASE = ((wm * 64 + (cl >> 1)) * 128) + (cl & 1) * 64;

  // ---- B fragment per-lane spatial decode ----
  int drf[2], owf[2];
#pragma unroll
  for (int nt = 0; nt < 2; ++nt) {
    int ln = wn * 64 + nt * 32 + cl;
    if (ln > BNR - 1) ln = BNR - 1;      // padded lanes clamp (stores guarded)
    drf[nt] = (ln >= 62) ? 1 : 0;
    owf[nt] = ln - drf[nt] * 62;
  }

  f32x16 acc[4][2] = {};

  char* ab[2] = { lds,          lds + 16384 };
  char* hb[2] = { lds + 32768,  lds + 49152 };

  auto STAGE_A = [&](int s, char* dst) {
    const int cc = s / 9, tap = s % 9;
    const int ak = tap * CIN + cc * 32;
#pragma unroll
    for (int q = 0; q < 4; ++q)
      gld16(Ap + aoff[q] + ak, dst + (wid * 4 + q) * 1024);
  };
  auto STAGE_H = [&](int cc, char* dst) {
#pragma unroll
    for (int q = 0; q < 4; ++q)
      gld16(Xp + hsrc[q] + cc * 32, dst + (wid * 4 + q) * 1024);
  };

  STAGE_H(0, hb[0]);
  STAGE_A(0, ab[0]);

#pragma unroll
  for (int s = 0; s < 36; ++s) {
    const int c = s / 9, tap = s % 9;
    const int kh = tap / 3, kw = tap - kh * 3;

    // wait for step-s data; keep halo prefetch (issued at s-1 if tap4) in flight
    if (s == 5 || s == 14 || s == 23)
      asm volatile("s_waitcnt vmcnt(4)" ::: "memory");
    else
      asm volatile("s_waitcnt vmcnt(0)" ::: "memory");
    __builtin_amdgcn_s_barrier();

    if (s + 1 < 36) STAGE_A(s + 1, ab[(s + 1) & 1]);
    if (tap == 4 && c < 3) STAGE_H(c + 1, hb[(c + 1) & 1]);

    const char* A = ab[s & 1];
    const char* H = hb[c & 1];

    bf16x8 a[4][2], b[2][2];
#pragma unroll
    for (int mt = 0; mt < 4; ++mt) {
      a[mt][0] = *reinterpret_cast<const bf16x8*>(A + ABASE + mt * 2048 + sw0);
      a[mt][1] = *reinterpret_cast<const bf16x8*>(A + ABASE + mt * 2048 + sw1);
    }
#pragma unroll
    for (int nt = 0; nt < 2; ++nt) {
      const int owp = owf[nt] + kw;                 // 0..63
      const int l2  = owp >> 1;
      const int line = (drf[nt] + kh) * 32 + l2;
      const int base = line * 128 + (owp & 1) * 64;
      const int k3   = line & 3;
      b[nt][0] = *reinterpret_cast<const bf16x8*>(H + base + (((gl)     ^ k3) * 16));
      b[nt][1] = *reinterpret_cast<const bf16x8*>(H + base + (((2 + gl) ^ k3) * 16));
    }

    __builtin_amdgcn_s_setprio(1);
#pragma unroll
    for (int kf = 0; kf < 2; ++kf)
#pragma unroll
      for (int mt = 0; mt < 4; ++mt)
#pragma unroll
        for (int nt = 0; nt < 2; ++nt)
          acc[mt][nt] = __builtin_amdgcn_mfma_f32_32x32x16_bf16(
              a[mt][kf], b[nt][kf], acc[mt][nt], 0, 0, 0);
    __builtin_amdgcn_s_setprio(0);
  }

  // ---- epilogue: 32x32 C/D col=lane&31, row=(r&3)+8*(r>>2)+4*gl ----
#pragma unroll
  for (int nt = 0; nt < 2; ++nt) {
    const int ln = wn * 64 + nt * 32 + cl;
    if (ln >= BNR) continue;                       // padded columns
    const int dr = (ln >= 62) ? 1 : 0;
    const int ow = ln - dr * 62;
    float* op = out + (size_t)bi * (COUT * NS) + (oh0 + dr) * OW + ow;
#pragma unroll
    for (int mt = 0; mt < 4; ++mt) {
      float* op2 = op + (size_t)(wm * 128 + mt * 32 + gl * 4) * NS;
#pragma unroll
      for (int r = 0; r < 16; ++r)
        op2[((r & 3) + 8 * (r >> 2)) * NS] = acc[mt][nt][r];
    }
  }
}

// ---------------- fallback (no-ws path, round-1 proven) ----------------

__global__ __launch_bounds__(256)
void conv_fallback(const float* __restrict__ x, const float* __restrict__ w,
                   float* __restrict__ out) {
  __shared__ __align__(16) unsigned short As[128 * 32];
  __shared__ __align__(16) unsigned short Bs[128 * 32];

  const int t    = threadIdx.x;
  const int lane = t & 63;
  const int wid  = t >> 6;
  const int wm   = wid >> 1;
  const int wn   = wid & 1;
  const int co_base = blockIdx.x * 128;
  const int n_base  = blockIdx.y * 128;

  const int bn  = t & 127;
  const int bg0 = t >> 7;
  const unsigned n0   = n_base + bn;
  const unsigned bidx = n0 / NS;
  const unsigned s0   = n0 - bidx * NS;
  const unsigned oh   = s0 / OW;
  const unsigned ow   = s0 - oh * OW;
  const float* xb = x + (bidx * (CIN * HW * HW) + oh * HW + ow);

  const int am  = t & 127;
  const int ag0 = (t >> 7) * 2;
  const float* wb = w + (co_base + am) * KTOT;

  f32x4 acc[4][4] = {};

  for (int ks = 0; ks < 36; ++ks) {
    const int tap = ks >> 2;
    const int ci0 = (ks & 3) * 32;
    const int kh  = tap / 3;
    const int kw  = tap - kh * 3;
    const int xo  = kh * HW + kw;

    float av[2][8], bv[2][8];
#pragma unroll
    for (int gi = 0; gi < 2; ++gi) {
      const int g = ag0 + gi;
#pragma unroll
      for (int j = 0; j < 8; ++j)
        av[gi][j] = wb[(ci0 + g * 8 + j) * 9 + tap];
    }
#pragma unroll
    for (int gi = 0; gi < 2; ++gi) {
      const int g = bg0 + gi * 2;
#pragma unroll
      for (int j = 0; j < 8; ++j)
        bv[gi][j] = xb[xo + (ci0 + g * 8 + j) * (HW * HW)];
    }

    __syncthreads();

#pragma unroll
    for (int gi = 0; gi < 2; ++gi) {
      const int g = ag0 + gi;
      uint4 pv;
      pv.x = pack2(av[gi][0], av[gi][1]);
      pv.y = pack2(av[gi][2], av[gi][3]);
      pv.z = pack2(av[gi][4], av[gi][5]);
      pv.w = pack2(av[gi][6], av[gi][7]);
      *reinterpret_cast<uint4*>(&As[am * 32 + ((g ^ ((am >> 1) & 3)) << 3)]) = pv;
    }
#pragma unroll
    for (int gi = 0; gi < 2; ++gi) {
      const int g = bg0 + gi * 2;
      uint4 pv;
      pv.x = pack2(bv[gi][0], bv[gi][1]);
      pv.y = pack2(bv[gi][2], bv[gi][3]);
      pv.z = pack2(bv[gi][4], bv[gi][5]);
      pv.w = pack2(bv[gi][6], bv[gi][7]);
      *reinterpret_cast<uint4*>(&Bs[bn * 32 + ((g ^ ((bn >> 1) & 3)) << 3)]) = pv;
    }

    __syncthreads();

    bf16x8 af[4], bfr[4];
    const int g = lane >> 4;
#pragma unroll
    for (int mi = 0; mi < 4; ++mi) {
      const int m = wm * 64 + mi * 16 + (lane & 15);
      af[mi] = *reinterpret_cast<const bf16x8*>(&As[m * 32 + ((g ^ ((m >> 1) & 3)) << 3)]);
    }
#pragma unroll
    for (int ni = 0; ni < 4; ++ni) {
      const int nn = wn * 64 + ni * 16 + (lane & 15);
      bfr[ni] = *reinterpret_cast<const bf16x8*>(&Bs[nn * 32 + ((g ^ ((nn >> 1) & 3)) << 3)]);
    }
#pragma unroll
    for (int mi = 0; mi < 4; ++mi)
#pragma unroll
      for (int ni = 0; ni < 4; ++ni)
        acc[mi][ni] = __builtin_amdgcn_mfma_f32_16x16x32_bf16(af[mi], bfr[ni],
                                                              acc[mi][ni], 0, 0, 0);
  }

#pragma unroll
  for (int ni = 0; ni < 4; ++ni) {
    const unsigned n  = n_base + wn * 64 + ni * 16 + (lane & 15);
    const unsigned b2 = n / NS;
    const unsigned s2 = n - b2 * NS;
    float* op = out + (size_t)b2 * (COUT * NS) + s2
                    + (size_t)(co_base + wm * 64 + (lane >> 4) * 4) * NS;
#pragma unroll
    for (int mi = 0; mi < 4; ++mi)
#pragma unroll
      for (int r = 0; r < 4; ++r)
        op[(mi * 16 + r) * NS] = acc[mi][ni][r];
  }
}

extern "C" void kernel_launch(void* const* d_in, const int* in_sizes, int n_in,
                              void* d_out, int out_size, void* d_ws, size_t ws_size,
                              hipStream_t stream) {
  const float* x = (const float*)d_in[0];   // [32,128,64,64]
  const float* w = (const float*)d_in[1];   // [256,128,3,3]
  float* out = (float*)d_out;               // [32,256,62,62]

  if (ws_size >= WS_NEEDED) {
    unsigned* ap32 = (unsigned*)d_ws;
    unsigned short* Ap = (unsigned short*)d_ws;
    unsigned short* Xp = (unsigned short*)((char*)d_ws + AP_BYTES);
    unsigned* xp32 = (unsigned*)Xp;
    prepack_w<<<576, 256, 0, stream>>>(w, ap32);
    prepack_x<<<32 * HW, 256, 0, stream>>>(x, xp32);
    conv_main<<<dim3(NPAN), 256, 0, stream>>>(Ap, Xp, out);
  } else {
    conv_fallback<<<dim3(2, NTOT / 128), 256, 0, stream>>>(x, w, out);
  }
}